// Round 4
// baseline (226.964 us; speedup 1.0000x reference)
//
#include <hip/hip_runtime.h>
#include <hip/hip_bf16.h>

// Swin3D MHSA: B=256 windows, N=392 tokens, DIM=128, H=4 heads, dh=32.
// R4: qkv/proj as BM=64 streaming GEMMs (grid 1568, W frags from L2);
//     qkv epilogue does block-LDS transpose -> fully coalesced 16B stores.
//     q/k stored token-major (t,128); vt stays (b,h,32,N). attn adapted.

typedef __attribute__((ext_vector_type(8))) short bf16x8;
typedef __attribute__((ext_vector_type(4))) float f32x4;
typedef __attribute__((ext_vector_type(4))) short s16x4;
typedef __attribute__((ext_vector_type(2))) unsigned int u32x2;

#define NTOK 392
#define NN (NTOK * NTOK)   // 153664
#define TABLE 2535         // 15*13*13
#define SCALE 0.17677669529663689f  // 1/sqrt(32)

__device__ __forceinline__ unsigned short f2bf(float f) {
  union { float f; unsigned u; } v; v.f = f;
  unsigned r = v.u + 0x7FFFu + ((v.u >> 16) & 1u);
  return (unsigned short)(r >> 16);
}
__device__ __forceinline__ float b2f(short s) {
  union { unsigned u; float f; } v;
  v.u = ((unsigned)(unsigned short)s) << 16;
  return v.f;
}
__device__ __forceinline__ unsigned pk2(float lo, float hi) {
  return (unsigned)f2bf(lo) | ((unsigned)f2bf(hi) << 16);
}

// ---------------- K0: one-time weight conversion f32 -> bf16 ----------------
__global__ __launch_bounds__(256) void wcvt_kernel(
    const float* __restrict__ Wqkv, const float* __restrict__ Wp,
    unsigned short* __restrict__ wqbf, unsigned short* __restrict__ wpbf) {
  int g = blockIdx.x * 256 + threadIdx.x;  // 16384 threads x 4 elems
  const float* src; unsigned short* dst; int off;
  if (g < 12288) { src = Wqkv; dst = wqbf; off = g * 4; }
  else           { src = Wp;   dst = wpbf; off = (g - 12288) * 4; }
  f32x4 v = *(const f32x4*)(src + off);
  s16x4 o;
  o[0] = (short)f2bf(v[0]); o[1] = (short)f2bf(v[1]);
  o[2] = (short)f2bf(v[2]); o[3] = (short)f2bf(v[3]);
  *(s16x4*)(dst + off) = o;
}

// ---------------- K1: bias in MFMA lane layout ----------------
__global__ __launch_bounds__(256) void biaspre_kernel(
    const float* __restrict__ rpb, const int* __restrict__ relidx,
    unsigned short* __restrict__ biaspre) {
  int g = blockIdx.x * 256 + threadIdx.x;  // 4*25*25*256 = 640000
  if (g >= 640000) return;
  int r = g & 3, lane = (g >> 2) & 63;
  int t = g >> 8;
  int jt = t % 25; int t2 = t / 25;
  int rb = t2 % 25; int h = t2 / 25;
  int q = rb * 16 + (lane & 15); if (q > 391) q = 391;
  int k = jt * 16 + (lane >> 4) * 4 + r; if (k > 391) k = 391;
  int f = q * (NTOK * 4) + k * 4 + h;   // raw (n,n,H) reshape quirk
  int hs = f / NN; int p = f - hs * NN;
  biaspre[g] = f2bf(rpb[hs * TABLE + relidx[p]]);
}

// ---------------- K2: QKV — streaming GEMM + LDS-transpose epilogue --------
// block: 64 tokens, 4 waves (wave = one 16-row m-subtile). grid 1568.
__global__ __launch_bounds__(256, 4) void qkv_kernel(
    const float* __restrict__ hidden, const unsigned short* __restrict__ wqbf,
    const float* __restrict__ bqkv,
    unsigned short* __restrict__ qbuf, unsigned short* __restrict__ kbuf,
    unsigned short* __restrict__ vtbuf) {
  __shared__ unsigned short X[9216];  // union: q/k [64][136]=8704, v [128][72]=9216
  const int tid = threadIdx.x;
  const int w = tid >> 6, lane = tid & 63, l15 = lane & 15, lhi = lane >> 4;
  const int row0 = blockIdx.x * 64;

  // A fragments (16 token rows per wave), converted once, reused 3x
  bf16x8 af[4];
#pragma unroll
  for (int kk = 0; kk < 4; ++kk) {
    const float* ap = hidden + ((size_t)(row0 + w * 16 + l15)) * 128 + kk * 32 + lhi * 8;
    f32x4 lo = *(const f32x4*)ap;
    f32x4 hi = *(const f32x4*)(ap + 4);
    bf16x8 a;
    a[0] = (short)f2bf(lo[0]); a[1] = (short)f2bf(lo[1]);
    a[2] = (short)f2bf(lo[2]); a[3] = (short)f2bf(lo[3]);
    a[4] = (short)f2bf(hi[0]); a[5] = (short)f2bf(hi[1]);
    a[6] = (short)f2bf(hi[2]); a[7] = (short)f2bf(hi[3]);
    af[kk] = a;
  }

  for (int s = 0; s < 3; ++s) {
    f32x4 acc[8];
#pragma unroll
    for (int jt = 0; jt < 8; ++jt) acc[jt] = 0.0f;
#pragma unroll
    for (int kk = 0; kk < 4; ++kk) {
#pragma unroll
      for (int jt = 0; jt < 8; ++jt) {
        bf16x8 wf = *(const bf16x8*)(
            wqbf + ((size_t)(s * 128 + jt * 16 + l15)) * 128 + kk * 32 + lhi * 8);
        acc[jt] = __builtin_amdgcn_mfma_f32_16x16x32_bf16(af[kk], wf, acc[jt], 0, 0, 0);
      }
    }

    if (s < 2) {
      // pack (bias, + scale for q) into LDS token-major [64][136]
      const float mul = (s == 0) ? SCALE : 1.0f;
#pragma unroll
      for (int jt = 0; jt < 8; ++jt) {
        float bias = bqkv[s * 128 + jt * 16 + l15];
#pragma unroll
        for (int r = 0; r < 4; ++r)
          X[(w * 16 + lhi * 4 + r) * 136 + jt * 16 + l15] =
              f2bf((acc[jt][r] + bias) * mul);
      }
      __syncthreads();
      unsigned short* dst = (s == 0) ? qbuf : kbuf;
#pragma unroll
      for (int it = 0; it < 4; ++it) {
        int i = it * 256 + tid;
        int rowi = i >> 4, c = i & 15;  // 16 chunks x 8 cols
        *(bf16x8*)&dst[((size_t)(row0 + rowi)) * 128 + c * 8] =
            *(const bf16x8*)&X[rowi * 136 + c * 8];
      }
      __syncthreads();
    } else {
      // v: LDS feature-major [128][72], 4 tokens packed per b64 write
#pragma unroll
      for (int jt = 0; jt < 8; ++jt) {
        float bias = bqkv[2 * 128 + jt * 16 + l15];
        u32x2 pkv;
        pkv[0] = pk2(acc[jt][0] + bias, acc[jt][1] + bias);
        pkv[1] = pk2(acc[jt][2] + bias, acc[jt][3] + bias);
        *(u32x2*)&X[(jt * 16 + l15) * 72 + w * 16 + lhi * 4] = pkv;
      }
      __syncthreads();
#pragma unroll
      for (int it = 0; it < 4; ++it) {
        int i = it * 256 + tid;
        int col = i >> 3, ch = i & 7;   // col 0..127, 8 token-chunks of 8
        int tg = row0 + ch * 8;         // multiple of 8; 392%8==0 -> no straddle
        int wb = tg / 392;
        int n0 = tg - wb * 392;
        *(bf16x8*)&vtbuf[(((size_t)wb * 4 + (col >> 5)) * 32 + (col & 31)) * NTOK + n0] =
            *(const bf16x8*)&X[col * 72 + ch * 8];
      }
    }
  }
}

// ---------------- K3: attention (swapped QK^T) ----------------
__global__ __launch_bounds__(256, 4) void attn_kernel(
    const unsigned short* __restrict__ qbuf, const unsigned short* __restrict__ kbuf,
    const unsigned short* __restrict__ vtbuf, const unsigned short* __restrict__ biaspre,
    unsigned short* __restrict__ ctxbuf) {
  __shared__ unsigned short Ksh[400][40];   // 32.0 KB, keys x dh
  __shared__ unsigned int Psh[4][16][20];   // 5.1 KB per-wave P tiles

  const int tid = threadIdx.x;
  const int w = tid >> 6, lane = tid & 63;
  const int l15 = lane & 15, lhi = lane >> 4;
  const int bh = blockIdx.x;
  const int h = bh & 3, b = bh >> 2;
  const size_t vtb = (size_t)bh * (NTOK * 32);

  for (int i = tid; i < 3136; i += 256) {   // K from token-major (t,128)
    int row = i >> 3, c4 = i & 7;
    *(s16x4*)&Ksh[row][c4 * 4] =
        *(const s16x4*)(kbuf + ((size_t)(b * NTOK + row)) * 128 + h * 32 + c4 * 4);
  }
  { int row = 392 + (tid >> 5); Ksh[row][tid & 31] = 0; }  // zero pad rows
  __syncthreads();

  const unsigned short* vbase = vtbuf + vtb;
  const s16x4* bias_lane =
      (const s16x4*)(biaspre + (size_t)h * 25 * 25 * 256 + (size_t)lane * 4);

  for (int rb = w; rb < 25; rb += 4) {
    int qrow = rb * 16 + l15; if (qrow > 391) qrow = 391;
    bf16x8 qf = *(const bf16x8*)(
        qbuf + ((size_t)(b * NTOK + qrow)) * 128 + h * 32 + lhi * 8);
    const s16x4* bp = bias_lane + (size_t)rb * 25 * 64;  // +jt*64 per jt

    f32x4 o0 = 0.0f, o1 = 0.0f;
    float ssum = 0.f;

    for (int g = 0; g < 12; ++g) {  // jt pairs (2g, 2g+1), all k valid
      int jt0 = 2 * g, jt1 = 2 * g + 1;
      bf16x8 kf0 = *(const bf16x8*)&Ksh[jt0 * 16 + l15][lhi * 8];
      bf16x8 kf1 = *(const bf16x8*)&Ksh[jt1 * 16 + l15][lhi * 8];
      f32x4 s0 = __builtin_amdgcn_mfma_f32_16x16x32_bf16(kf0, qf, (f32x4)0.f, 0, 0, 0);
      f32x4 s1 = __builtin_amdgcn_mfma_f32_16x16x32_bf16(kf1, qf, (f32x4)0.f, 0, 0, 0);
      s16x4 bv0 = bp[jt0 * 64];
      s16x4 bv1 = bp[jt1 * 64];
      float e00 = __expf(s0[0] + b2f(bv0[0])), e01 = __expf(s0[1] + b2f(bv0[1]));
      float e02 = __expf(s0[2] + b2f(bv0[2])), e03 = __expf(s0[3] + b2f(bv0[3]));
      float e10 = __expf(s1[0] + b2f(bv1[0])), e11 = __expf(s1[1] + b2f(bv1[1]));
      float e12 = __expf(s1[2] + b2f(bv1[2])), e13 = __expf(s1[3] + b2f(bv1[3]));
      ssum += (e00 + e01 + e02 + e03) + (e10 + e11 + e12 + e13);
      u32x2 wlo; wlo[0] = pk2(e00, e01); wlo[1] = pk2(e02, e03);
      u32x2 whi; whi[0] = pk2(e10, e11); whi[1] = pk2(e12, e13);
      *(u32x2*)&Psh[w][l15][lhi * 2] = wlo;       // k cols lhi*4..+3
      *(u32x2*)&Psh[w][l15][8 + lhi * 2] = whi;   // k cols 16+lhi*4..+3
      bf16x8 pf = *(const bf16x8*)&Psh[w][l15][lhi * 4];
      bf16x8 vf0 = *(const bf16x8*)(vbase + (size_t)l15 * NTOK + g * 32 + lhi * 8);
      bf16x8 vf1 = *(const bf16x8*)(vbase + (size_t)(16 + l15) * NTOK + g * 32 + lhi * 8);
      o0 = __builtin_amdgcn_mfma_f32_16x16x32_bf16(pf, vf0, o0, 0, 0, 0);
      o1 = __builtin_amdgcn_mfma_f32_16x16x32_bf16(pf, vf1, o1, 0, 0, 0);
    }
    {  // g = 12: jt0 = 24 (k 384..391 valid only for lhi<2), jt1 absent
      bf16x8 kf0 = *(const bf16x8*)&Ksh[384 + l15][lhi * 8];
      f32x4 s0 = __builtin_amdgcn_mfma_f32_16x16x32_bf16(kf0, qf, (f32x4)0.f, 0, 0, 0);
      s16x4 bv0 = bp[24 * 64];
      float e00 = __expf(s0[0] + b2f(bv0[0])), e01 = __expf(s0[1] + b2f(bv0[1]));
      float e02 = __expf(s0[2] + b2f(bv0[2])), e03 = __expf(s0[3] + b2f(bv0[3]));
      if (lhi >= 2) { e00 = 0.f; e01 = 0.f; e02 = 0.f; e03 = 0.f; }
      ssum += (e00 + e01) + (e02 + e03);
      u32x2 wlo; wlo[0] = pk2(e00, e01); wlo[1] = pk2(e02, e03);
      u32x2 whi; whi[0] = 0u; whi[1] = 0u;
      *(u32x2*)&Psh[w][l15][lhi * 2] = wlo;
      *(u32x2*)&Psh[w][l15][8 + lhi * 2] = whi;
      bf16x8 pf = *(const bf16x8*)&Psh[w][l15][lhi * 4];
      bf16x8 vf0 = *(const bf16x8*)(vbase + (size_t)l15 * NTOK + 384 + lhi * 8);
      bf16x8 vf1 = *(const bf16x8*)(vbase + (size_t)(16 + l15) * NTOK + 384 + lhi * 8);
      o0 = __builtin_amdgcn_mfma_f32_16x16x32_bf16(pf, vf0, o0, 0, 0, 0);
      o1 = __builtin_amdgcn_mfma_f32_16x16x32_bf16(pf, vf1, o1, 0, 0, 0);
    }

    // total row sums: lanes sharing l15 (stride 16) hold partials
    ssum += __shfl_xor(ssum, 16);
    ssum += __shfl_xor(ssum, 32);
    float rtot = 1.f / ssum;   // valid for q-row = l15 (all lhi copies)
    float rr[4];
#pragma unroll
    for (int r = 0; r < 4; ++r) rr[r] = __shfl(rtot, lhi * 4 + r);

#pragma unroll
    for (int r = 0; r < 4; ++r) {
      int row = rb * 16 + lhi * 4 + r;
      if (row < NTOK) {
        unsigned short* crow = ctxbuf + ((size_t)(b * NTOK) + row) * 128 + h * 32;
        crow[l15] = f2bf(o0[r] * rr[r]);
        crow[16 + l15] = f2bf(o1[r] * rr[r]);
      }
    }
  }
}

// ---------------- K4: output projection — streaming, BM=64 ----------------
__global__ __launch_bounds__(256, 4) void proj_kernel(
    const unsigned short* __restrict__ ctxbuf, const unsigned short* __restrict__ wpbf,
    const float* __restrict__ bp, float* __restrict__ out) {
  const int tid = threadIdx.x;
  const int w = tid >> 6, lane = tid & 63, l15 = lane & 15, lhi = lane >> 4;
  const int trow = blockIdx.x * 64 + w * 16;

  bf16x8 af[4];
#pragma unroll
  for (int kk = 0; kk < 4; ++kk)
    af[kk] = *(const bf16x8*)(
        ctxbuf + ((size_t)(trow + l15)) * 128 + kk * 32 + lhi * 8);

  f32x4 acc[8];
#pragma unroll
  for (int jt = 0; jt < 8; ++jt) acc[jt] = 0.0f;
#pragma unroll
  for (int kk = 0; kk < 4; ++kk) {
#pragma unroll
    for (int jt = 0; jt < 8; ++jt) {
      bf16x8 wf = *(const bf16x8*)(
          wpbf + ((size_t)(jt * 16 + l15)) * 128 + kk * 32 + lhi * 8);
      acc[jt] = __builtin_amdgcn_mfma_f32_16x16x32_bf16(af[kk], wf, acc[jt], 0, 0, 0);
    }
  }
#pragma unroll
  for (int jt = 0; jt < 8; ++jt) {
    int colL = jt * 16 + l15;
    float bias = bp[colL];
#pragma unroll
    for (int r = 0; r < 4; ++r) {
      int t = trow + lhi * 4 + r;
      out[(size_t)t * 128 + colL] = acc[jt][r] + bias;
    }
  }
}

// ---------------- launch ----------------
extern "C" void kernel_launch(void* const* d_in, const int* in_sizes, int n_in,
                              void* d_out, int out_size, void* d_ws, size_t ws_size,
                              hipStream_t stream) {
  const float* hidden = (const float*)d_in[0];
  const float* Wqkv = (const float*)d_in[1];
  const float* bqkv = (const float*)d_in[2];
  const float* Wp = (const float*)d_in[3];
  const float* bp = (const float*)d_in[4];
  const float* rpb = (const float*)d_in[5];
  const int* relidx = (const int*)d_in[6];

  // ws: q | k | vt(+pad) | ctx (bf16, 12,845,056 each) | biaspre | wq_bf | wp_bf
  unsigned short* qbuf = (unsigned short*)d_ws;
  unsigned short* kbuf = qbuf + 12845056;
  unsigned short* vtbuf = kbuf + 12845056;
  unsigned short* ctxbuf = vtbuf + 12845056 + 1024;  // pad: attn V reads overshoot
  unsigned short* biaspre = ctxbuf + 12845056;
  unsigned short* wqbf = biaspre + 640000;
  unsigned short* wpbf = wqbf + 49152;

  wcvt_kernel<<<64, 256, 0, stream>>>(Wqkv, Wp, wqbf, wpbf);
  biaspre_kernel<<<2500, 256, 0, stream>>>(rpb, relidx, biaspre);
  qkv_kernel<<<1568, 256, 0, stream>>>(hidden, wqbf, bqkv, qbuf, kbuf, vtbuf);
  attn_kernel<<<1024, 256, 0, stream>>>(qbuf, kbuf, vtbuf, biaspre, ctxbuf);
  proj_kernel<<<1568, 256, 0, stream>>>(ctxbuf, wpbf, bp, (float*)d_out);
}

// Round 6
// 192.195 us; speedup vs baseline: 1.1809x; 1.1809x over previous
//
#include <hip/hip_runtime.h>
#include <hip/hip_bf16.h>

// Swin3D MHSA: B=256 windows, N=392 tokens, DIM=128, H=4 heads, dh=32.
// R6: R5 mega-kernel with the Vtsh pad-init bug fixed (rows 16..31 of the
//     col-392..423 pad were never zeroed -> 0*NaN in PV MFMA).
//     Structure: fused qkv+attention (1 block/window, 8 waves), then proj.

typedef __attribute__((ext_vector_type(8))) short bf16x8;
typedef __attribute__((ext_vector_type(4))) float f32x4;
typedef __attribute__((ext_vector_type(4))) short s16x4;
typedef __attribute__((ext_vector_type(2))) unsigned int u32x2;

#define NTOK 392
#define NN (NTOK * NTOK)   // 153664
#define TABLE 2535         // 15*13*13
#define SCALE 0.17677669529663689f  // 1/sqrt(32)

__device__ __forceinline__ unsigned short f2bf(float f) {
  union { float f; unsigned u; } v; v.f = f;
  unsigned r = v.u + 0x7FFFu + ((v.u >> 16) & 1u);
  return (unsigned short)(r >> 16);
}
__device__ __forceinline__ float b2f(short s) {
  union { unsigned u; float f; } v;
  v.u = ((unsigned)(unsigned short)s) << 16;
  return v.f;
}
__device__ __forceinline__ unsigned pk2(float lo, float hi) {
  return (unsigned)f2bf(lo) | ((unsigned)f2bf(hi) << 16);
}

// ---------------- K0: one-time weight conversion f32 -> bf16 ----------------
__global__ __launch_bounds__(256) void wcvt_kernel(
    const float* __restrict__ Wqkv, const float* __restrict__ Wp,
    unsigned short* __restrict__ wqbf, unsigned short* __restrict__ wpbf) {
  int g = blockIdx.x * 256 + threadIdx.x;  // 16384 threads x 4 elems
  const float* src; unsigned short* dst; int off;
  if (g < 12288) { src = Wqkv; dst = wqbf; off = g * 4; }
  else           { src = Wp;   dst = wpbf; off = (g - 12288) * 4; }
  f32x4 v = *(const f32x4*)(src + off);
  s16x4 o;
  o[0] = (short)f2bf(v[0]); o[1] = (short)f2bf(v[1]);
  o[2] = (short)f2bf(v[2]); o[3] = (short)f2bf(v[3]);
  *(s16x4*)(dst + off) = o;
}

// ---------------- K1: bias in MFMA lane layout ----------------
__global__ __launch_bounds__(256) void biaspre_kernel(
    const float* __restrict__ rpb, const int* __restrict__ relidx,
    unsigned short* __restrict__ biaspre) {
  int g = blockIdx.x * 256 + threadIdx.x;  // 4*25*25*256 = 640000
  if (g >= 640000) return;
  int r = g & 3, lane = (g >> 2) & 63;
  int t = g >> 8;
  int jt = t % 25; int t2 = t / 25;
  int rb = t2 % 25; int h = t2 / 25;
  int q = rb * 16 + (lane & 15); if (q > 391) q = 391;
  int k = jt * 16 + (lane >> 4) * 4 + r; if (k > 391) k = 391;
  int f = q * (NTOK * 4) + k * 4 + h;   // raw (n,n,H) reshape quirk
  int hs = f / NN; int p = f - hs * NN;
  biaspre[g] = f2bf(rpb[hs * TABLE + relidx[p]]);
}

// ---------------- K2: MEGA — fused QKV + attention, 1 block per window -----
__global__ __launch_bounds__(512, 2) void mega_kernel(
    const float* __restrict__ hidden, const unsigned short* __restrict__ wqbf,
    const float* __restrict__ bqkv, const unsigned short* __restrict__ biaspre,
    unsigned short* __restrict__ ctxbuf) {
  __shared__ unsigned short Qsh[400][40];   // 32000 B
  __shared__ unsigned short Ksh[400][40];   // 32000 B
  __shared__ unsigned short Vtsh[32][424];  // 27136 B
  __shared__ unsigned int Psh[8][16][20];   // 10240 B  (total ~99.0 KB)

  const int tid = threadIdx.x;              // 0..511
  const int w = tid >> 6, lane = tid & 63;
  const int l15 = lane & 15, lhi = lane >> 4;
  const int b = blockIdx.x;

  // zero pads once: K pad rows 392..399 (cols 0..39); Vt pad cols 392..423
  // for ALL 32 rows (R5 bug: rows 16..31 were left uninitialized -> NaN).
  { int r = tid >> 6, c = tid & 63; if (c < 40) Ksh[392 + r][c] = 0; }
  { int row = tid >> 5, col = tid & 31;       // row 0..15
    Vtsh[row][392 + col] = 0;
    Vtsh[16 + row][392 + col] = 0; }

  const float* hwin = hidden + (size_t)b * NTOK * 128;

  for (int h = 0; h < 4; ++h) {
    __syncthreads();  // h=0: cover pad init; h>0: previous attn done reading LDS

    // ---- QKV GEMMs for head h: Q->Qsh, K->Ksh, V^T->Vtsh ----
    float bq[2], bk[2], bv[2];
#pragma unroll
    for (int jt = 0; jt < 2; ++jt) {
      int d = h * 32 + jt * 16 + l15;
      bq[jt] = bqkv[d]; bk[jt] = bqkv[128 + d]; bv[jt] = bqkv[256 + d];
    }
    for (int mt = w; mt < 25; mt += 8) {
      bf16x8 af[4];
      int arow = mt * 16 + l15; if (arow > 391) arow = 391;
#pragma unroll
      for (int kk = 0; kk < 4; ++kk) {
        const float* ap = hwin + (size_t)arow * 128 + kk * 32 + lhi * 8;
        f32x4 lo = *(const f32x4*)ap;
        f32x4 hi = *(const f32x4*)(ap + 4);
        bf16x8 a;
        a[0] = (short)f2bf(lo[0]); a[1] = (short)f2bf(lo[1]);
        a[2] = (short)f2bf(lo[2]); a[3] = (short)f2bf(lo[3]);
        a[4] = (short)f2bf(hi[0]); a[5] = (short)f2bf(hi[1]);
        a[6] = (short)f2bf(hi[2]); a[7] = (short)f2bf(hi[3]);
        af[kk] = a;
      }
      const int tok0 = mt * 16 + lhi * 4;
#pragma unroll
      for (int ss = 0; ss < 3; ++ss) {
        f32x4 acc[2]; acc[0] = 0.0f; acc[1] = 0.0f;
#pragma unroll
        for (int kk = 0; kk < 4; ++kk)
#pragma unroll
          for (int jt = 0; jt < 2; ++jt) {
            bf16x8 wf = *(const bf16x8*)(
                wqbf + ((size_t)(ss * 128 + h * 32 + jt * 16 + l15)) * 128 +
                kk * 32 + lhi * 8);
            acc[jt] = __builtin_amdgcn_mfma_f32_16x16x32_bf16(af[kk], wf, acc[jt], 0, 0, 0);
          }
        if (ss == 0) {
#pragma unroll
          for (int jt = 0; jt < 2; ++jt)
#pragma unroll
            for (int r = 0; r < 4; ++r) {
              int t = tok0 + r;
              if (t < NTOK) Qsh[t][jt * 16 + l15] = f2bf((acc[jt][r] + bq[jt]) * SCALE);
            }
        } else if (ss == 1) {
#pragma unroll
          for (int jt = 0; jt < 2; ++jt)
#pragma unroll
            for (int r = 0; r < 4; ++r) {
              int t = tok0 + r;
              if (t < NTOK) Ksh[t][jt * 16 + l15] = f2bf(acc[jt][r] + bk[jt]);
            }
        } else {
          if (tok0 < NTOK) {  // mt=24, lhi>=2 -> skip (pad cols stay zero)
#pragma unroll
            for (int jt = 0; jt < 2; ++jt) {
              u32x2 pv;
              pv[0] = pk2(acc[jt][0] + bv[jt], acc[jt][1] + bv[jt]);
              pv[1] = pk2(acc[jt][2] + bv[jt], acc[jt][3] + bv[jt]);
              *(u32x2*)&Vtsh[jt * 16 + l15][tok0] = pv;
            }
          }
        }
      }
    }
    __syncthreads();

    // ---- attention for head h (swapped QK^T; Q/K/Vt from LDS) ----
    const s16x4* bias_lane =
        (const s16x4*)(biaspre + (size_t)h * 25 * 25 * 256 + (size_t)lane * 4);

    for (int rb = w; rb < 25; rb += 8) {
      int qrow = rb * 16 + l15; if (qrow > 391) qrow = 391;
      bf16x8 qf = *(const bf16x8*)&Qsh[qrow][lhi * 8];
      const s16x4* bp = bias_lane + (size_t)rb * 25 * 64;

      f32x4 o0 = 0.0f, o1 = 0.0f;
      float ssum = 0.f;

      for (int g = 0; g < 12; ++g) {
        int jt0 = 2 * g, jt1 = 2 * g + 1;
        bf16x8 kf0 = *(const bf16x8*)&Ksh[jt0 * 16 + l15][lhi * 8];
        bf16x8 kf1 = *(const bf16x8*)&Ksh[jt1 * 16 + l15][lhi * 8];
        f32x4 s0 = __builtin_amdgcn_mfma_f32_16x16x32_bf16(kf0, qf, (f32x4)0.f, 0, 0, 0);
        f32x4 s1 = __builtin_amdgcn_mfma_f32_16x16x32_bf16(kf1, qf, (f32x4)0.f, 0, 0, 0);
        s16x4 bv0 = bp[jt0 * 64];
        s16x4 bv1 = bp[jt1 * 64];
        float e00 = __expf(s0[0] + b2f(bv0[0])), e01 = __expf(s0[1] + b2f(bv0[1]));
        float e02 = __expf(s0[2] + b2f(bv0[2])), e03 = __expf(s0[3] + b2f(bv0[3]));
        float e10 = __expf(s1[0] + b2f(bv1[0])), e11 = __expf(s1[1] + b2f(bv1[1]));
        float e12 = __expf(s1[2] + b2f(bv1[2])), e13 = __expf(s1[3] + b2f(bv1[3]));
        ssum += (e00 + e01 + e02 + e03) + (e10 + e11 + e12 + e13);
        u32x2 wlo; wlo[0] = pk2(e00, e01); wlo[1] = pk2(e02, e03);
        u32x2 whi; whi[0] = pk2(e10, e11); whi[1] = pk2(e12, e13);
        *(u32x2*)&Psh[w][l15][lhi * 2] = wlo;
        *(u32x2*)&Psh[w][l15][8 + lhi * 2] = whi;
        bf16x8 pf = *(const bf16x8*)&Psh[w][l15][lhi * 4];
        bf16x8 vf0 = *(const bf16x8*)&Vtsh[l15][g * 32 + lhi * 8];
        bf16x8 vf1 = *(const bf16x8*)&Vtsh[16 + l15][g * 32 + lhi * 8];
        o0 = __builtin_amdgcn_mfma_f32_16x16x32_bf16(pf, vf0, o0, 0, 0, 0);
        o1 = __builtin_amdgcn_mfma_f32_16x16x32_bf16(pf, vf1, o1, 0, 0, 0);
      }
      {  // jt0 = 24 (k 384..391 valid only for lhi<2)
        bf16x8 kf0 = *(const bf16x8*)&Ksh[384 + l15][lhi * 8];
        f32x4 s0 = __builtin_amdgcn_mfma_f32_16x16x32_bf16(kf0, qf, (f32x4)0.f, 0, 0, 0);
        s16x4 bv0 = bp[24 * 64];
        float e00 = __expf(s0[0] + b2f(bv0[0])), e01 = __expf(s0[1] + b2f(bv0[1]));
        float e02 = __expf(s0[2] + b2f(bv0[2])), e03 = __expf(s0[3] + b2f(bv0[3]));
        if (lhi >= 2) { e00 = 0.f; e01 = 0.f; e02 = 0.f; e03 = 0.f; }
        ssum += (e00 + e01) + (e02 + e03);
        u32x2 wlo; wlo[0] = pk2(e00, e01); wlo[1] = pk2(e02, e03);
        u32x2 whi; whi[0] = 0u; whi[1] = 0u;
        *(u32x2*)&Psh[w][l15][lhi * 2] = wlo;
        *(u32x2*)&Psh[w][l15][8 + lhi * 2] = whi;
        bf16x8 pf = *(const bf16x8*)&Psh[w][l15][lhi * 4];
        bf16x8 vf0 = *(const bf16x8*)&Vtsh[l15][384 + lhi * 8];
        bf16x8 vf1 = *(const bf16x8*)&Vtsh[16 + l15][384 + lhi * 8];
        o0 = __builtin_amdgcn_mfma_f32_16x16x32_bf16(pf, vf0, o0, 0, 0, 0);
        o1 = __builtin_amdgcn_mfma_f32_16x16x32_bf16(pf, vf1, o1, 0, 0, 0);
      }

      ssum += __shfl_xor(ssum, 16);
      ssum += __shfl_xor(ssum, 32);
      float rtot = 1.f / ssum;
      float rr[4];
#pragma unroll
      for (int r = 0; r < 4; ++r) rr[r] = __shfl(rtot, lhi * 4 + r);

#pragma unroll
      for (int r = 0; r < 4; ++r) {
        int row = rb * 16 + lhi * 4 + r;
        if (row < NTOK) {
          unsigned short* crow = ctxbuf + ((size_t)(b * NTOK) + row) * 128 + h * 32;
          crow[l15] = f2bf(o0[r] * rr[r]);
          crow[16 + l15] = f2bf(o1[r] * rr[r]);
        }
      }
    }
  }
}

// ---------------- K3: output projection — streaming, nt stores -------------
__global__ __launch_bounds__(256, 4) void proj_kernel(
    const unsigned short* __restrict__ ctxbuf, const unsigned short* __restrict__ wpbf,
    const float* __restrict__ bp, float* __restrict__ out) {
  const int tid = threadIdx.x;
  const int w = tid >> 6, lane = tid & 63, l15 = lane & 15, lhi = lane >> 4;
  const int trow = blockIdx.x * 64 + w * 16;

  bf16x8 af[4];
#pragma unroll
  for (int kk = 0; kk < 4; ++kk)
    af[kk] = *(const bf16x8*)(
        ctxbuf + ((size_t)(trow + l15)) * 128 + kk * 32 + lhi * 8);

  f32x4 acc[8];
#pragma unroll
  for (int jt = 0; jt < 8; ++jt) acc[jt] = 0.0f;
#pragma unroll
  for (int kk = 0; kk < 4; ++kk) {
#pragma unroll
    for (int jt = 0; jt < 8; ++jt) {
      bf16x8 wf = *(const bf16x8*)(
          wpbf + ((size_t)(jt * 16 + l15)) * 128 + kk * 32 + lhi * 8);
      acc[jt] = __builtin_amdgcn_mfma_f32_16x16x32_bf16(af[kk], wf, acc[jt], 0, 0, 0);
    }
  }
#pragma unroll
  for (int jt = 0; jt < 8; ++jt) {
    int colL = jt * 16 + l15;
    float bias = bp[colL];
#pragma unroll
    for (int r = 0; r < 4; ++r) {
      int t = trow + lhi * 4 + r;
      __builtin_nontemporal_store(acc[jt][r] + bias, &out[(size_t)t * 128 + colL]);
    }
  }
}

// ---------------- launch ----------------
extern "C" void kernel_launch(void* const* d_in, const int* in_sizes, int n_in,
                              void* d_out, int out_size, void* d_ws, size_t ws_size,
                              hipStream_t stream) {
  const float* hidden = (const float*)d_in[0];
  const float* Wqkv = (const float*)d_in[1];
  const float* bqkv = (const float*)d_in[2];
  const float* Wp = (const float*)d_in[3];
  const float* bp = (const float*)d_in[4];
  const float* rpb = (const float*)d_in[5];
  const int* relidx = (const int*)d_in[6];

  // ws: ctx (12,845,056 bf16) | biaspre (640,000) | wq_bf (49,152) | wp_bf (16,384)
  unsigned short* ctxbuf = (unsigned short*)d_ws;
  unsigned short* biaspre = ctxbuf + 12845056;
  unsigned short* wqbf = biaspre + 640000;
  unsigned short* wpbf = wqbf + 49152;

  wcvt_kernel<<<64, 256, 0, stream>>>(Wqkv, Wp, wqbf, wpbf);
  biaspre_kernel<<<2500, 256, 0, stream>>>(rpb, relidx, biaspre);
  mega_kernel<<<256, 512, 0, stream>>>(hidden, wqbf, bqkv, biaspre, ctxbuf);
  proj_kernel<<<1568, 256, 0, stream>>>(ctxbuf, wpbf, bp, (float*)d_out);
}

// Round 7
// 183.866 us; speedup vs baseline: 1.2344x; 1.0453x over previous
//
#include <hip/hip_runtime.h>
#include <hip/hip_bf16.h>

// Swin3D MHSA: B=256 windows, N=392 tokens, DIM=128, H=4 heads, dh=32.
// R7: fused qkv+attention mega-kernel, 1024 threads (16 waves, 4/SIMD):
//     - A fragments (hidden) loaded+converted ONCE into registers (was 4x)
//     - Qsh dropped: Q transposed through per-wave WB buffer into registers
//     - LDS 99 -> 77.8 KB; occupancy 2 -> 4 waves/SIMD
//     proj: streaming GEMM with nontemporal f32 stores (unchanged).

typedef __attribute__((ext_vector_type(8))) short bf16x8;
typedef __attribute__((ext_vector_type(4))) float f32x4;
typedef __attribute__((ext_vector_type(4))) short s16x4;
typedef __attribute__((ext_vector_type(2))) unsigned int u32x2;

#define NTOK 392
#define NN (NTOK * NTOK)   // 153664
#define TABLE 2535         // 15*13*13
#define SCALE 0.17677669529663689f  // 1/sqrt(32)

__device__ __forceinline__ unsigned short f2bf(float f) {
  union { float f; unsigned u; } v; v.f = f;
  unsigned r = v.u + 0x7FFFu + ((v.u >> 16) & 1u);
  return (unsigned short)(r >> 16);
}
__device__ __forceinline__ float b2f(short s) {
  union { unsigned u; float f; } v;
  v.u = ((unsigned)(unsigned short)s) << 16;
  return v.f;
}
__device__ __forceinline__ unsigned pk2(float lo, float hi) {
  return (unsigned)f2bf(lo) | ((unsigned)f2bf(hi) << 16);
}

// ---------------- K0: one-time weight conversion f32 -> bf16 ----------------
__global__ __launch_bounds__(256) void wcvt_kernel(
    const float* __restrict__ Wqkv, const float* __restrict__ Wp,
    unsigned short* __restrict__ wqbf, unsigned short* __restrict__ wpbf) {
  int g = blockIdx.x * 256 + threadIdx.x;  // 16384 threads x 4 elems
  const float* src; unsigned short* dst; int off;
  if (g < 12288) { src = Wqkv; dst = wqbf; off = g * 4; }
  else           { src = Wp;   dst = wpbf; off = (g - 12288) * 4; }
  f32x4 v = *(const f32x4*)(src + off);
  s16x4 o;
  o[0] = (short)f2bf(v[0]); o[1] = (short)f2bf(v[1]);
  o[2] = (short)f2bf(v[2]); o[3] = (short)f2bf(v[3]);
  *(s16x4*)(dst + off) = o;
}

// ---------------- K1: bias in MFMA lane layout ----------------
__global__ __launch_bounds__(256) void biaspre_kernel(
    const float* __restrict__ rpb, const int* __restrict__ relidx,
    unsigned short* __restrict__ biaspre) {
  int g = blockIdx.x * 256 + threadIdx.x;  // 4*25*25*256 = 640000
  if (g >= 640000) return;
  int r = g & 3, lane = (g >> 2) & 63;
  int t = g >> 8;
  int jt = t % 25; int t2 = t / 25;
  int rb = t2 % 25; int h = t2 / 25;
  int q = rb * 16 + (lane & 15); if (q > 391) q = 391;
  int k = jt * 16 + (lane >> 4) * 4 + r; if (k > 391) k = 391;
  int f = q * (NTOK * 4) + k * 4 + h;   // raw (n,n,H) reshape quirk
  int hs = f / NN; int p = f - hs * NN;
  biaspre[g] = f2bf(rpb[hs * TABLE + relidx[p]]);
}

// ---------------- K2: MEGA — fused QKV + attention ----------------
// 1 block per window, 1024 threads = 16 waves; wave w owns m-tiles {w, w+16}.
__global__ __launch_bounds__(1024, 4) void mega_kernel(
    const float* __restrict__ hidden, const unsigned short* __restrict__ wqbf,
    const float* __restrict__ bqkv, const unsigned short* __restrict__ biaspre,
    unsigned short* __restrict__ ctxbuf) {
  __shared__ unsigned short Ksh[400][40];     // 32000 B (stride 80B, b128-aligned)
  __shared__ unsigned short Vtsh[32][424];    // 27136 B
  __shared__ unsigned short WB[16][16][40];   // 20480 B per-wave Q-transpose / P tiles
                                              // total 79616 B

  const int tid = threadIdx.x;                // 0..1023
  const int w = tid >> 6, lane = tid & 63;
  const int l15 = lane & 15, lhi = lane >> 4;
  const int b = blockIdx.x;

  // zero pads once: Ksh rows 392..399 (all 40 cols); Vtsh cols 392..423 x 32 rows
  if (tid < 512) { int r = tid >> 6, c = tid & 63; if (c < 40) Ksh[392 + r][c] = 0; }
  Vtsh[tid >> 5][392 + (tid & 31)] = 0;

  const float* hwin = hidden + (size_t)b * NTOK * 128;

  // ---- A fragments: loaded + converted ONCE, reused for all heads/slices ----
  bf16x8 afr[2][4];
#pragma unroll
  for (int i = 0; i < 2; ++i) {
    int mt = w + i * 16;
    if (mt < 25) {
      int arow = mt * 16 + l15; if (arow > 391) arow = 391;
#pragma unroll
      for (int kk = 0; kk < 4; ++kk) {
        const float* ap = hwin + (size_t)arow * 128 + kk * 32 + lhi * 8;
        f32x4 lo = *(const f32x4*)ap;
        f32x4 hi = *(const f32x4*)(ap + 4);
        bf16x8 a;
        a[0] = (short)f2bf(lo[0]); a[1] = (short)f2bf(lo[1]);
        a[2] = (short)f2bf(lo[2]); a[3] = (short)f2bf(lo[3]);
        a[4] = (short)f2bf(hi[0]); a[5] = (short)f2bf(hi[1]);
        a[6] = (short)f2bf(hi[2]); a[7] = (short)f2bf(hi[3]);
        afr[i][kk] = a;
      }
    }
  }

  for (int h = 0; h < 4; ++h) {
    __syncthreads();  // h=0: covers pad init; h>0: prev attn done reading LDS

    float bq[2], bk[2], bv[2];
#pragma unroll
    for (int jt = 0; jt < 2; ++jt) {
      int d = h * 32 + jt * 16 + l15;
      bq[jt] = bqkv[d]; bk[jt] = bqkv[128 + d]; bv[jt] = bqkv[256 + d];
    }

    bf16x8 qreg[2];
#pragma unroll
    for (int i = 0; i < 2; ++i) {
      int mt = w + i * 16;
      if (mt >= 25) continue;
      const int tok0 = mt * 16 + lhi * 4;

      // ---- Q slice: MFMA -> per-wave WB transpose -> register fragment ----
      {
        f32x4 acc0 = 0.0f, acc1 = 0.0f;
#pragma unroll
        for (int kk = 0; kk < 4; ++kk) {
          const unsigned short* wp0 =
              wqbf + ((size_t)(h * 32 + l15)) * 128 + kk * 32 + lhi * 8;
          bf16x8 wf0 = *(const bf16x8*)wp0;
          bf16x8 wf1 = *(const bf16x8*)(wp0 + 16 * 128);
          acc0 = __builtin_amdgcn_mfma_f32_16x16x32_bf16(afr[i][kk], wf0, acc0, 0, 0, 0);
          acc1 = __builtin_amdgcn_mfma_f32_16x16x32_bf16(afr[i][kk], wf1, acc1, 0, 0, 0);
        }
#pragma unroll
        for (int r = 0; r < 4; ++r) {
          WB[w][lhi * 4 + r][l15]      = f2bf((acc0[r] + bq[0]) * SCALE);
          WB[w][lhi * 4 + r][16 + l15] = f2bf((acc1[r] + bq[1]) * SCALE);
        }
        qreg[i] = *(const bf16x8*)&WB[w][l15][lhi * 8];
      }
      // ---- K slice -> Ksh[token][dh] ----
      {
        f32x4 acc0 = 0.0f, acc1 = 0.0f;
#pragma unroll
        for (int kk = 0; kk < 4; ++kk) {
          const unsigned short* wp0 =
              wqbf + ((size_t)(128 + h * 32 + l15)) * 128 + kk * 32 + lhi * 8;
          bf16x8 wf0 = *(const bf16x8*)wp0;
          bf16x8 wf1 = *(const bf16x8*)(wp0 + 16 * 128);
          acc0 = __builtin_amdgcn_mfma_f32_16x16x32_bf16(afr[i][kk], wf0, acc0, 0, 0, 0);
          acc1 = __builtin_amdgcn_mfma_f32_16x16x32_bf16(afr[i][kk], wf1, acc1, 0, 0, 0);
        }
#pragma unroll
        for (int r = 0; r < 4; ++r) {
          int t = tok0 + r;
          if (t < NTOK) {
            Ksh[t][l15]      = f2bf(acc0[r] + bk[0]);
            Ksh[t][16 + l15] = f2bf(acc1[r] + bk[1]);
          }
        }
      }
      // ---- V slice -> Vtsh[dh][token] (packed) ----
      {
        f32x4 acc0 = 0.0f, acc1 = 0.0f;
#pragma unroll
        for (int kk = 0; kk < 4; ++kk) {
          const unsigned short* wp0 =
              wqbf + ((size_t)(256 + h * 32 + l15)) * 128 + kk * 32 + lhi * 8;
          bf16x8 wf0 = *(const bf16x8*)wp0;
          bf16x8 wf1 = *(const bf16x8*)(wp0 + 16 * 128);
          acc0 = __builtin_amdgcn_mfma_f32_16x16x32_bf16(afr[i][kk], wf0, acc0, 0, 0, 0);
          acc1 = __builtin_amdgcn_mfma_f32_16x16x32_bf16(afr[i][kk], wf1, acc1, 0, 0, 0);
        }
        if (tok0 < NTOK) {
          u32x2 pv;
          pv[0] = pk2(acc0[0] + bv[0], acc0[1] + bv[0]);
          pv[1] = pk2(acc0[2] + bv[0], acc0[3] + bv[0]);
          *(u32x2*)&Vtsh[l15][tok0] = pv;
          pv[0] = pk2(acc1[0] + bv[1], acc1[1] + bv[1]);
          pv[1] = pk2(acc1[2] + bv[1], acc1[3] + bv[1]);
          *(u32x2*)&Vtsh[16 + l15][tok0] = pv;
        }
      }
    }
    __syncthreads();

    // ---- attention for head h (swapped QK^T; K/Vt from LDS, Q from regs) ----
    const s16x4* bias_lane =
        (const s16x4*)(biaspre + (size_t)h * 25 * 25 * 256 + (size_t)lane * 4);
    unsigned* Pw = (unsigned*)&WB[w][0][0];   // [16][20] u32 view, stride 80B

#pragma unroll
    for (int i = 0; i < 2; ++i) {
      int rb = w + i * 16;
      if (rb >= 25) continue;
      bf16x8 qf = qreg[i];
      const s16x4* bp = bias_lane + (size_t)rb * 25 * 64;

      f32x4 o0 = 0.0f, o1 = 0.0f;
      float ssum = 0.f;

      for (int g = 0; g < 12; ++g) {
        int jt0 = 2 * g, jt1 = 2 * g + 1;
        bf16x8 kf0 = *(const bf16x8*)&Ksh[jt0 * 16 + l15][lhi * 8];
        bf16x8 kf1 = *(const bf16x8*)&Ksh[jt1 * 16 + l15][lhi * 8];
        f32x4 s0 = __builtin_amdgcn_mfma_f32_16x16x32_bf16(kf0, qf, (f32x4)0.f, 0, 0, 0);
        f32x4 s1 = __builtin_amdgcn_mfma_f32_16x16x32_bf16(kf1, qf, (f32x4)0.f, 0, 0, 0);
        s16x4 bv0 = bp[jt0 * 64];
        s16x4 bv1 = bp[jt1 * 64];
        float e00 = __expf(s0[0] + b2f(bv0[0])), e01 = __expf(s0[1] + b2f(bv0[1]));
        float e02 = __expf(s0[2] + b2f(bv0[2])), e03 = __expf(s0[3] + b2f(bv0[3]));
        float e10 = __expf(s1[0] + b2f(bv1[0])), e11 = __expf(s1[1] + b2f(bv1[1]));
        float e12 = __expf(s1[2] + b2f(bv1[2])), e13 = __expf(s1[3] + b2f(bv1[3]));
        ssum += (e00 + e01 + e02 + e03) + (e10 + e11 + e12 + e13);
        u32x2 wlo; wlo[0] = pk2(e00, e01); wlo[1] = pk2(e02, e03);
        u32x2 whi; whi[0] = pk2(e10, e11); whi[1] = pk2(e12, e13);
        *(u32x2*)&Pw[l15 * 20 + lhi * 2] = wlo;
        *(u32x2*)&Pw[l15 * 20 + 8 + lhi * 2] = whi;
        bf16x8 pf = *(const bf16x8*)&Pw[l15 * 20 + lhi * 4];
        bf16x8 vf0 = *(const bf16x8*)&Vtsh[l15][g * 32 + lhi * 8];
        bf16x8 vf1 = *(const bf16x8*)&Vtsh[16 + l15][g * 32 + lhi * 8];
        o0 = __builtin_amdgcn_mfma_f32_16x16x32_bf16(pf, vf0, o0, 0, 0, 0);
        o1 = __builtin_amdgcn_mfma_f32_16x16x32_bf16(pf, vf1, o1, 0, 0, 0);
      }
      {  // jt0 = 24 (keys 384..391 valid only for lhi<2)
        bf16x8 kf0 = *(const bf16x8*)&Ksh[384 + l15][lhi * 8];
        f32x4 s0 = __builtin_amdgcn_mfma_f32_16x16x32_bf16(kf0, qf, (f32x4)0.f, 0, 0, 0);
        s16x4 bv0 = bp[24 * 64];
        float e00 = __expf(s0[0] + b2f(bv0[0])), e01 = __expf(s0[1] + b2f(bv0[1]));
        float e02 = __expf(s0[2] + b2f(bv0[2])), e03 = __expf(s0[3] + b2f(bv0[3]));
        if (lhi >= 2) { e00 = 0.f; e01 = 0.f; e02 = 0.f; e03 = 0.f; }
        ssum += (e00 + e01) + (e02 + e03);
        u32x2 wlo; wlo[0] = pk2(e00, e01); wlo[1] = pk2(e02, e03);
        u32x2 whi; whi[0] = 0u; whi[1] = 0u;
        *(u32x2*)&Pw[l15 * 20 + lhi * 2] = wlo;
        *(u32x2*)&Pw[l15 * 20 + 8 + lhi * 2] = whi;
        bf16x8 pf = *(const bf16x8*)&Pw[l15 * 20 + lhi * 4];
        bf16x8 vf0 = *(const bf16x8*)&Vtsh[l15][384 + lhi * 8];
        bf16x8 vf1 = *(const bf16x8*)&Vtsh[16 + l15][384 + lhi * 8];
        o0 = __builtin_amdgcn_mfma_f32_16x16x32_bf16(pf, vf0, o0, 0, 0, 0);
        o1 = __builtin_amdgcn_mfma_f32_16x16x32_bf16(pf, vf1, o1, 0, 0, 0);
      }

      ssum += __shfl_xor(ssum, 16);
      ssum += __shfl_xor(ssum, 32);
      float rtot = 1.f / ssum;
      float rr[4];
#pragma unroll
      for (int r = 0; r < 4; ++r) rr[r] = __shfl(rtot, lhi * 4 + r);

#pragma unroll
      for (int r = 0; r < 4; ++r) {
        int row = rb * 16 + lhi * 4 + r;
        if (row < NTOK) {
          unsigned short* crow = ctxbuf + ((size_t)(b * NTOK) + row) * 128 + h * 32;
          crow[l15] = f2bf(o0[r] * rr[r]);
          crow[16 + l15] = f2bf(o1[r] * rr[r]);
        }
      }
    }
  }
}

// ---------------- K3: output projection — streaming, nt stores -------------
__global__ __launch_bounds__(256, 4) void proj_kernel(
    const unsigned short* __restrict__ ctxbuf, const unsigned short* __restrict__ wpbf,
    const float* __restrict__ bp, float* __restrict__ out) {
  const int tid = threadIdx.x;
  const int w = tid >> 6, lane = tid & 63, l15 = lane & 15, lhi = lane >> 4;
  const int trow = blockIdx.x * 64 + w * 16;

  bf16x8 af[4];
#pragma unroll
  for (int kk = 0; kk < 4; ++kk)
    af[kk] = *(const bf16x8*)(
        ctxbuf + ((size_t)(trow + l15)) * 128 + kk * 32 + lhi * 8);

  f32x4 acc[8];
#pragma unroll
  for (int jt = 0; jt < 8; ++jt) acc[jt] = 0.0f;
#pragma unroll
  for (int kk = 0; kk < 4; ++kk) {
#pragma unroll
    for (int jt = 0; jt < 8; ++jt) {
      bf16x8 wf = *(const bf16x8*)(
          wpbf + ((size_t)(jt * 16 + l15)) * 128 + kk * 32 + lhi * 8);
      acc[jt] = __builtin_amdgcn_mfma_f32_16x16x32_bf16(af[kk], wf, acc[jt], 0, 0, 0);
    }
  }
#pragma unroll
  for (int jt = 0; jt < 8; ++jt) {
    int colL = jt * 16 + l15;
    float bias = bp[colL];
#pragma unroll
    for (int r = 0; r < 4; ++r) {
      int t = trow + lhi * 4 + r;
      __builtin_nontemporal_store(acc[jt][r] + bias, &out[(size_t)t * 128 + colL]);
    }
  }
}

// ---------------- launch ----------------
extern "C" void kernel_launch(void* const* d_in, const int* in_sizes, int n_in,
                              void* d_out, int out_size, void* d_ws, size_t ws_size,
                              hipStream_t stream) {
  const float* hidden = (const float*)d_in[0];
  const float* Wqkv = (const float*)d_in[1];
  const float* bqkv = (const float*)d_in[2];
  const float* Wp = (const float*)d_in[3];
  const float* bp = (const float*)d_in[4];
  const float* rpb = (const float*)d_in[5];
  const int* relidx = (const int*)d_in[6];

  // ws: ctx (12,845,056 bf16) | biaspre (640,000) | wq_bf (49,152) | wp_bf (16,384)
  unsigned short* ctxbuf = (unsigned short*)d_ws;
  unsigned short* biaspre = ctxbuf + 12845056;
  unsigned short* wqbf = biaspre + 640000;
  unsigned short* wpbf = wqbf + 49152;

  wcvt_kernel<<<64, 256, 0, stream>>>(Wqkv, Wp, wqbf, wpbf);
  biaspre_kernel<<<2500, 256, 0, stream>>>(rpb, relidx, biaspre);
  mega_kernel<<<256, 1024, 0, stream>>>(hidden, wqbf, bqkv, biaspre, ctxbuf);
  proj_kernel<<<1568, 256, 0, stream>>>(ctxbuf, wpbf, bp, (float*)d_out);
}